// Round 10
// baseline (255.092 us; speedup 1.0000x reference)
//
#include <hip/hip_runtime.h>
#include <hip/hip_fp16.h>

#define FDIM 128
#define HEADS 4
#define CD 32
#define BM 32

static __device__ __forceinline__ unsigned short f2bf(float v) {
    unsigned u = __float_as_uint(v);
    u += 0x7FFF + ((u >> 16) & 1);          // round-nearest-even
    return (unsigned short)(u >> 16);
}
static __device__ __forceinline__ float bf2f(unsigned short u) {
    return __uint_as_float(((unsigned)u) << 16);
}

// K1: fused GEMM + logits (+ accumulator zeroing in prologue).
// BM=32 rows/block, 4x4 thread tile, 16.9 KB LDS -> 8 blocks/CU.
// Logits computed by register shuffle-reduce (no LDS round-trip).
__global__ __launch_bounds__(256) void k_gemm(const float* __restrict__ x,
                                              const float* __restrict__ w,
                                              const float* __restrict__ att,
                                              unsigned short* __restrict__ xwh,
                                              float* __restrict__ a_src,
                                              float* __restrict__ a_dst,
                                              float4* __restrict__ zero_base,
                                              int nz4, int N)
{
    __shared__ float xs[FDIM * 33];      // [k][row], padded
    int t = threadIdx.x;
    int row0 = blockIdx.x * BM;
    for (int i = blockIdx.x * 256 + t; i < nz4; i += gridDim.x * 256)
        zero_base[i] = make_float4(0.f, 0.f, 0.f, 0.f);
#pragma unroll
    for (int it = 0; it < 4; it++) {
        int i = t + 256 * it;            // 0..1023
        int row = i >> 5, kq = i & 31;   // lanes vary kq -> coalesced 512B/row reads
        float4 v = make_float4(0.f, 0.f, 0.f, 0.f);
        if (row0 + row < N) v = ((const float4*)x)[(size_t)(row0 + row) * 32 + kq];
        xs[(kq * 4 + 0) * 33 + row] = v.x;
        xs[(kq * 4 + 1) * 33 + row] = v.y;
        xs[(kq * 4 + 2) * 33 + row] = v.z;
        xs[(kq * 4 + 3) * 33 + row] = v.w;
    }
    __syncthreads();
    int tx = t & 31, ty = t >> 5;
    int c0 = tx * 4, r0 = ty * 4;
    const float4* w4 = (const float4*)w;
    float acc[4][4];
#pragma unroll
    for (int i = 0; i < 4; i++)
#pragma unroll
        for (int j = 0; j < 4; j++) acc[i][j] = 0.f;
#pragma unroll 4
    for (int k = 0; k < FDIM; k++) {
        float4 wv = w4[k * 32 + tx];                    // L1/L2 broadcast
        float4 xa = *(const float4*)&xs[k * 33 + r0];   // broadcast in ty group
        float xr[4] = {xa.x, xa.y, xa.z, xa.w};
        float wr[4] = {wv.x, wv.y, wv.z, wv.w};
#pragma unroll
        for (int i = 0; i < 4; i++)
#pragma unroll
            for (int j = 0; j < 4; j++) acc[i][j] += xr[i] * wr[j];
    }
    // store bf16 head-interleaved  xwh[r*128 + ch*4 + h]
    int h = tx >> 3, chb = c0 & 31;
#pragma unroll
    for (int i = 0; i < 4; i++) {
        int r = row0 + r0 + i;
        if (r < N) {
#pragma unroll
            for (int j = 0; j < 4; j++)
                xwh[(size_t)r * FDIM + (chb + j) * 4 + h] = f2bf(acc[i][j]);
        }
    }
    // logits: 8 lanes (sub=tx&7) per head group hold the 32 channels of head h
    int sub = tx & 7;
    const float* ap = att + h * 2 * CD + sub * 4;       // src weights; +32 for dst
    float sv[4], dv[4];
#pragma unroll
    for (int i = 0; i < 4; i++) {
        sv[i] = acc[i][0] * ap[0] + acc[i][1] * ap[1] + acc[i][2] * ap[2] + acc[i][3] * ap[3];
        dv[i] = acc[i][0] * ap[32] + acc[i][1] * ap[33] + acc[i][2] * ap[34] + acc[i][3] * ap[35];
    }
#pragma unroll
    for (int m = 1; m <= 4; m <<= 1) {
#pragma unroll
        for (int i = 0; i < 4; i++) {
            sv[i] += __shfl_xor(sv[i], m, 64);
            dv[i] += __shfl_xor(dv[i], m, 64);
        }
    }
    if (sub == 0) {
#pragma unroll
        for (int i = 0; i < 4; i++) {
            int n = row0 + r0 + i;
            if (n < N) { a_src[n * 4 + h] = sv[i]; a_dst[n * 4 + h] = dv[i]; }
        }
    }
}

// K4: one thread per EDGE: two float4 gathers, 4 exps, one 8B ealpha store,
// two pk-f16 atomics into seg (8 B footprint, 1 sector per edge).
__global__ __launch_bounds__(256) void k_esum(const int* __restrict__ ei, int E,
                                              const float* __restrict__ a_src,
                                              const float* __restrict__ a_dst,
                                              __half2* __restrict__ seg2,
                                              __half* __restrict__ ealpha)
{
    int e = blockIdx.x * 256 + threadIdx.x;
    if (e >= E) return;
    int r = ei[e], cl = ei[E + e];
    float4 as = *(const float4*)&a_src[r * 4];
    float4 ad = *(const float4*)&a_dst[cl * 4];
    float a0 = as.x + ad.x, a1 = as.y + ad.y, a2 = as.z + ad.z, a3 = as.w + ad.w;
    a0 = a0 >= 0.f ? a0 : 0.2f * a0;
    a1 = a1 >= 0.f ? a1 : 0.2f * a1;
    a2 = a2 >= 0.f ? a2 : 0.2f * a2;
    a3 = a3 >= 0.f ? a3 : 0.2f * a3;
    __half2 p0 = __floats2half2_rn(__expf(a0), __expf(a1));
    __half2 p1 = __floats2half2_rn(__expf(a2), __expf(a3));
    uint2 pkd;
    pkd.x = *reinterpret_cast<unsigned*>(&p0);
    pkd.y = *reinterpret_cast<unsigned*>(&p1);
    ((uint2*)ealpha)[e] = pkd;
    unsafeAtomicAdd(&seg2[(size_t)r * 2], p0);
    unsafeAtomicAdd(&seg2[(size_t)r * 2 + 1], p1);
}

// K5: out_acc2 += packed fp16 pair — 16 lanes/edge, 64 B atomic footprint.
__global__ __launch_bounds__(256) void k_scatter(const int* __restrict__ ei, int E,
                                                 const __half* __restrict__ ealpha,
                                                 const __half* __restrict__ seg,
                                                 const unsigned short* __restrict__ xwh,
                                                 __half2* __restrict__ out_acc2)
{
    int t = threadIdx.x;
    int le = t >> 4, c2 = t & 15;
    int e = blockIdx.x * 16 + le;
    if (e >= E) return;
    int r = ei[e], cl = ei[E + e];
    int lane = t & 63;
    float av = 0.f;
    if (c2 < 4)
        av = 0.25f * __half2float(ealpha[e * 4 + c2]) /
             (__half2float(seg[r * 4 + c2]) + 1e-16f);
    uint4 q = ((const uint4*)(xwh + (size_t)r * FDIM))[c2];
    float a0 = __shfl(av, (lane & 48) + 0, 64);
    float a1 = __shfl(av, (lane & 48) + 1, 64);
    float a2 = __shfl(av, (lane & 48) + 2, 64);
    float a3 = __shfl(av, (lane & 48) + 3, 64);
    float v0 = a0 * bf2f((unsigned short)(q.x & 0xFFFF)) + a1 * bf2f((unsigned short)(q.x >> 16))
             + a2 * bf2f((unsigned short)(q.y & 0xFFFF)) + a3 * bf2f((unsigned short)(q.y >> 16));
    float v1 = a0 * bf2f((unsigned short)(q.z & 0xFFFF)) + a1 * bf2f((unsigned short)(q.z >> 16))
             + a2 * bf2f((unsigned short)(q.w & 0xFFFF)) + a3 * bf2f((unsigned short)(q.w >> 16));
    unsafeAtomicAdd(&out_acc2[(size_t)cl * 16 + c2], __floats2half2_rn(v0, v1));
}

// K6: out = fp16 out_acc2 + bias
__global__ void k_final(const __half2* __restrict__ out_acc2, const float4* __restrict__ bias,
                        float4* __restrict__ out, int N)
{
    int i = blockIdx.x * 256 + threadIdx.x;
    if (i >= N * 8) return;
    float4 b = bias[i & 7];
    float2 f0 = __half22float2(out_acc2[i * 2]);
    float2 f1 = __half22float2(out_acc2[i * 2 + 1]);
    out[i] = make_float4(f0.x + b.x, f0.y + b.y, f1.x + b.z, f1.y + b.w);
}

extern "C" void kernel_launch(void* const* d_in, const int* in_sizes, int n_in,
                              void* d_out, int out_size, void* d_ws, size_t ws_size,
                              hipStream_t stream)
{
    const float* x    = (const float*)d_in[0];
    const int*   ei   = (const int*)d_in[1];
    const float* w    = (const float*)d_in[2];
    const float* att  = (const float*)d_in[3];
    const float* bias = (const float*)d_in[4];
    float* out = (float*)d_out;
    int N = in_sizes[0] / FDIM;
    int E = in_sizes[1] / 2;

    unsigned short* xwh = (unsigned short*)d_ws;              // N*128 bf16  (12.8 MB)
    float* fws      = (float*)(xwh + (size_t)N * FDIM);
    float* a_src    = fws;                                    // N*4 f32
    float* a_dst    = a_src + (size_t)N * HEADS;              // N*4 f32
    __half* seg     = (__half*)(a_dst + (size_t)N * HEADS);   // N*4 fp16  (zeroed)
    __half2* out_acc2 = (__half2*)(seg + (size_t)N * HEADS);  // N*16 half2 (zeroed, contig)
    __half* ealpha  = (__half*)(out_acc2 + (size_t)N * 16);   // E*4 fp16

    // zero region: seg (N*8 B) + out_acc2 (N*64 B) = N*72 B
    int nz4 = (N * 9) / 2;

    k_gemm<<<(N + BM - 1) / BM, 256, 0, stream>>>(x, w, att, xwh, a_src, a_dst,
                                                  (float4*)seg, nz4, N);
    k_esum<<<(E + 255) / 256, 256, 0, stream>>>(ei, E, a_src, a_dst,
                                                (__half2*)seg, ealpha);
    k_scatter<<<(E + 15) / 16, 256, 0, stream>>>(ei, E, ealpha, seg, xwh, out_acc2);
    k_final<<<(N * 8 + 255) / 256, 256, 0, stream>>>(out_acc2, (const float4*)bias, (float4*)out, N);
}

// Round 11
// 211.658 us; speedup vs baseline: 1.2052x; 1.2052x over previous
//
#include <hip/hip_runtime.h>
#include <hip/hip_fp16.h>

#define FDIM 128
#define HEADS 4
#define CD 32
#define BM 32

static __device__ __forceinline__ unsigned short f2bf(float v) {
    unsigned u = __float_as_uint(v);
    u += 0x7FFF + ((u >> 16) & 1);          // round-nearest-even
    return (unsigned short)(u >> 16);
}
static __device__ __forceinline__ float bf2f(unsigned short u) {
    return __uint_as_float(((unsigned)u) << 16);
}

// K1: fused GEMM + logits (+ accumulator zeroing in prologue).
// BM=32 rows/block, 4x4 thread tile, ~17 KB LDS -> high occupancy.
// Logits computed by register shuffle-reduce (no LDS round-trip).
__global__ __launch_bounds__(256) void k_gemm(const float* __restrict__ x,
                                              const float* __restrict__ w,
                                              const float* __restrict__ att,
                                              unsigned short* __restrict__ xwh,
                                              float* __restrict__ a_src,
                                              float* __restrict__ a_dst,
                                              float4* __restrict__ zero_base,
                                              int nz4, int N)
{
    __shared__ float xs[FDIM * 33];      // [k][row], padded
    int t = threadIdx.x;
    int row0 = blockIdx.x * BM;
    for (int i = blockIdx.x * 256 + t; i < nz4; i += gridDim.x * 256)
        zero_base[i] = make_float4(0.f, 0.f, 0.f, 0.f);
#pragma unroll
    for (int it = 0; it < 4; it++) {
        int i = t + 256 * it;            // 0..1023
        int row = i >> 5, kq = i & 31;   // lanes vary kq -> coalesced reads
        float4 v = make_float4(0.f, 0.f, 0.f, 0.f);
        if (row0 + row < N) v = ((const float4*)x)[(size_t)(row0 + row) * 32 + kq];
        xs[(kq * 4 + 0) * 33 + row] = v.x;
        xs[(kq * 4 + 1) * 33 + row] = v.y;
        xs[(kq * 4 + 2) * 33 + row] = v.z;
        xs[(kq * 4 + 3) * 33 + row] = v.w;
    }
    __syncthreads();
    int tx = t & 31, ty = t >> 5;
    int c0 = tx * 4, r0 = ty * 4;
    const float4* w4 = (const float4*)w;
    float acc[4][4];
#pragma unroll
    for (int i = 0; i < 4; i++)
#pragma unroll
        for (int j = 0; j < 4; j++) acc[i][j] = 0.f;
#pragma unroll 4
    for (int k = 0; k < FDIM; k++) {
        float4 wv = w4[k * 32 + tx];                    // L1/L2 broadcast
        float4 xa = *(const float4*)&xs[k * 33 + r0];   // broadcast in ty group
        float xr[4] = {xa.x, xa.y, xa.z, xa.w};
        float wr[4] = {wv.x, wv.y, wv.z, wv.w};
#pragma unroll
        for (int i = 0; i < 4; i++)
#pragma unroll
            for (int j = 0; j < 4; j++) acc[i][j] += xr[i] * wr[j];
    }
    // store bf16 head-interleaved  xwh[r*128 + ch*4 + h]
    int h = tx >> 3, chb = c0 & 31;
#pragma unroll
    for (int i = 0; i < 4; i++) {
        int r = row0 + r0 + i;
        if (r < N) {
#pragma unroll
            for (int j = 0; j < 4; j++)
                xwh[(size_t)r * FDIM + (chb + j) * 4 + h] = f2bf(acc[i][j]);
        }
    }
    // logits: 8 lanes (sub=tx&7) per head group hold the 32 channels of head h
    int sub = tx & 7;
    const float* ap = att + h * 2 * CD + sub * 4;       // src weights; +32 for dst
    float sv[4], dv[4];
#pragma unroll
    for (int i = 0; i < 4; i++) {
        sv[i] = acc[i][0] * ap[0] + acc[i][1] * ap[1] + acc[i][2] * ap[2] + acc[i][3] * ap[3];
        dv[i] = acc[i][0] * ap[32] + acc[i][1] * ap[33] + acc[i][2] * ap[34] + acc[i][3] * ap[35];
    }
#pragma unroll
    for (int m = 1; m <= 4; m <<= 1) {
#pragma unroll
        for (int i = 0; i < 4; i++) {
            sv[i] += __shfl_xor(sv[i], m, 64);
            dv[i] += __shfl_xor(dv[i], m, 64);
        }
    }
    if (sub == 0) {
#pragma unroll
        for (int i = 0; i < 4; i++) {
            int n = row0 + r0 + i;
            if (n < N) { a_src[n * 4 + h] = sv[i]; a_dst[n * 4 + h] = dv[i]; }
        }
    }
}

// K4: one thread per (edge,head). 4 lanes share an edge -> gathers coalesce to
// one sector each; lanes h=0,2 issue ONE pk-f16 atomic pair in the SAME
// instruction -> HW merges to 1 line-RMW per edge (the measured floor).
__global__ __launch_bounds__(256) void k_esum(const int* __restrict__ ei, int E,
                                              const float* __restrict__ a_src,
                                              const float* __restrict__ a_dst,
                                              __half2* __restrict__ seg2,
                                              __half* __restrict__ ealpha)
{
    int gid = blockIdx.x * 256 + threadIdx.x;
    if (gid >= E * HEADS) return;
    int e = gid >> 2, h = gid & 3;
    int r = ei[e], cl = ei[E + e];
    float a = a_src[r * 4 + h] + a_dst[cl * 4 + h];
    a = a >= 0.f ? a : 0.2f * a;
    float ex = __expf(a);
    ealpha[gid] = __float2half(ex);
    float exn = __shfl_down(ex, 1, 64);     // neighbor lane's (h+1) value
    if ((h & 1) == 0)
        unsafeAtomicAdd(&seg2[(size_t)r * 2 + (h >> 1)], __floats2half2_rn(ex, exn));
}

// K5: out_acc2 += packed fp16 pair — 16 lanes/edge, one 64B line-RMW per edge.
__global__ __launch_bounds__(256) void k_scatter(const int* __restrict__ ei, int E,
                                                 const __half* __restrict__ ealpha,
                                                 const __half* __restrict__ seg,
                                                 const unsigned short* __restrict__ xwh,
                                                 __half2* __restrict__ out_acc2)
{
    int t = threadIdx.x;
    int le = t >> 4, c2 = t & 15;
    int e = blockIdx.x * 16 + le;
    if (e >= E) return;
    int r = ei[e], cl = ei[E + e];
    int lane = t & 63;
    float av = 0.f;
    if (c2 < 4)
        av = 0.25f * __half2float(ealpha[e * 4 + c2]) /
             (__half2float(seg[r * 4 + c2]) + 1e-16f);
    uint4 q = ((const uint4*)(xwh + (size_t)r * FDIM))[c2];
    float a0 = __shfl(av, (lane & 48) + 0, 64);
    float a1 = __shfl(av, (lane & 48) + 1, 64);
    float a2 = __shfl(av, (lane & 48) + 2, 64);
    float a3 = __shfl(av, (lane & 48) + 3, 64);
    float v0 = a0 * bf2f((unsigned short)(q.x & 0xFFFF)) + a1 * bf2f((unsigned short)(q.x >> 16))
             + a2 * bf2f((unsigned short)(q.y & 0xFFFF)) + a3 * bf2f((unsigned short)(q.y >> 16));
    float v1 = a0 * bf2f((unsigned short)(q.z & 0xFFFF)) + a1 * bf2f((unsigned short)(q.z >> 16))
             + a2 * bf2f((unsigned short)(q.w & 0xFFFF)) + a3 * bf2f((unsigned short)(q.w >> 16));
    unsafeAtomicAdd(&out_acc2[(size_t)cl * 16 + c2], __floats2half2_rn(v0, v1));
}

// K6: out = fp16 out_acc2 + bias
__global__ void k_final(const __half2* __restrict__ out_acc2, const float4* __restrict__ bias,
                        float4* __restrict__ out, int N)
{
    int i = blockIdx.x * 256 + threadIdx.x;
    if (i >= N * 8) return;
    float4 b = bias[i & 7];
    float2 f0 = __half22float2(out_acc2[i * 2]);
    float2 f1 = __half22float2(out_acc2[i * 2 + 1]);
    out[i] = make_float4(f0.x + b.x, f0.y + b.y, f1.x + b.z, f1.y + b.w);
}

extern "C" void kernel_launch(void* const* d_in, const int* in_sizes, int n_in,
                              void* d_out, int out_size, void* d_ws, size_t ws_size,
                              hipStream_t stream)
{
    const float* x    = (const float*)d_in[0];
    const int*   ei   = (const int*)d_in[1];
    const float* w    = (const float*)d_in[2];
    const float* att  = (const float*)d_in[3];
    const float* bias = (const float*)d_in[4];
    float* out = (float*)d_out;
    int N = in_sizes[0] / FDIM;
    int E = in_sizes[1] / 2;

    unsigned short* xwh = (unsigned short*)d_ws;              // N*128 bf16  (12.8 MB)
    float* fws      = (float*)(xwh + (size_t)N * FDIM);
    float* a_src    = fws;                                    // N*4 f32
    float* a_dst    = a_src + (size_t)N * HEADS;              // N*4 f32
    __half* seg     = (__half*)(a_dst + (size_t)N * HEADS);   // N*4 fp16  (zeroed)
    __half2* out_acc2 = (__half2*)(seg + (size_t)N * HEADS);  // N*16 half2 (zeroed, contig)
    __half* ealpha  = (__half*)(out_acc2 + (size_t)N * 16);   // E*4 fp16

    // zero region: seg (N*8 B) + out_acc2 (N*64 B) = N*72 B
    int nz4 = (N * 9) / 2;

    k_gemm<<<(N + BM - 1) / BM, 256, 0, stream>>>(x, w, att, xwh, a_src, a_dst,
                                                  (float4*)seg, nz4, N);
    k_esum<<<(E * HEADS + 255) / 256, 256, 0, stream>>>(ei, E, a_src, a_dst,
                                                        (__half2*)seg, ealpha);
    k_scatter<<<(E + 15) / 16, 256, 0, stream>>>(ei, E, ealpha, seg, xwh, out_acc2);
    k_final<<<(N * 8 + 255) / 256, 256, 0, stream>>>(out_acc2, (const float4*)bias, (float4*)out, N);
}